// Round 2
// baseline (15525.673 us; speedup 1.0000x reference)
//
#include <hip/hip_runtime.h>
#include <hip/hip_bf16.h>

#define B_     2048
#define DIM_   1024
#define CLS_   1024
#define ODIM_  1024
#define DEPTH_ 4
#define SEQ_   8
#define INNER_ 128
#define DH_    64
#define FFI_   2048
#define ROT_   32

// ---------------- threefry2x32 (matches jax._src.prng, 20 rounds) ----------------
__host__ __device__ inline void tf2x32(unsigned k0, unsigned k1, unsigned& x0, unsigned& x1)
{
  unsigned ks2 = k0 ^ k1 ^ 0x1BD11BDAu;
  x0 += k0; x1 += k1;
#define TFR(r) { x0 += x1; x1 = (x1 << (r)) | (x1 >> (32 - (r))); x1 ^= x0; }
  TFR(13) TFR(15) TFR(26) TFR(6)
  x0 += k1;  x1 += ks2 + 1u;
  TFR(17) TFR(29) TFR(16) TFR(24)
  x0 += ks2; x1 += k0 + 2u;
  TFR(13) TFR(15) TFR(26) TFR(6)
  x0 += k0;  x1 += k1 + 3u;
  TFR(17) TFR(29) TFR(16) TFR(24)
  x0 += k1;  x1 += ks2 + 4u;
  TFR(13) TFR(15) TFR(26) TFR(6)
  x0 += ks2; x1 += k0 + 5u;
#undef TFR
}

__device__ inline float gelu_tanh(float x) {
  float t = tanhf(0.7978845608028654f * (x + 0.044715f * (x * x * x)));
  float cdf = 0.5f * (1.0f + t);
  return x * cdf;
}

// ---------------- rmsnorm: out = x*g / sqrt(mean(x^2)+1e-8) ----------------
__global__ __launch_bounds__(256) void rmsnorm_k(const float* __restrict__ x,
    const float* __restrict__ g, float* __restrict__ out)
{
  int b = blockIdx.x, tid = threadIdx.x;
  const float4* xr = (const float4*)(x + (size_t)b * DIM_);
  float4 v = xr[tid];
  float ss = v.x * v.x + v.y * v.y + v.z * v.z + v.w * v.w;
#pragma unroll
  for (int m = 32; m; m >>= 1) ss += __shfl_xor(ss, m);
  __shared__ float red[4];
  if ((tid & 63) == 0) red[tid >> 6] = ss;
  __syncthreads();
  float tot = red[0] + red[1] + red[2] + red[3];
  float denom = sqrtf(tot * (1.0f / DIM_) + 1e-8f);
  float4 gv = ((const float4*)g)[tid];
  float4 o;
  o.x = v.x * gv.x / denom; o.y = v.y * gv.y / denom;
  o.z = v.z * gv.z / denom; o.w = v.w * gv.w / denom;
  ((float4*)(out + (size_t)b * DIM_))[tid] = o;
}

// ---------------- tiled fp32 GEMM. A:MxK row, B:KxN row, C:Mx(ldc) ----------------
// EPI: 0=none, 1=C+=  (residual, reads C), 2=+bias X[col]
template<int BM, int TM, int EPI>
__global__ __launch_bounds__(256) void gemm_k(
    const float* __restrict__ A, const float* __restrict__ Bw,
    float* __restrict__ C, const float* __restrict__ X,
    int N, int K, int ldc)
{
  constexpr int BN = 64, BK = 16, TN = 4;
  __shared__ float As[BK][BM + 4];
  __shared__ float Bs[BK][BN + 4];
  const int tid = threadIdx.x;
  const int tx = tid & 15, ty = tid >> 4;
  const int bm = blockIdx.y * BM, bn = blockIdx.x * BN;
  const int brow = tid >> 4, bcol = (tid & 15) * 4;
  float acc[TM][TN] = {};
  for (int k0 = 0; k0 < K; k0 += BK) {
    if constexpr (BM == 64) {
      const int arow = tid >> 2, acol = (tid & 3) * 4;
      float4 av = *(const float4*)(A + (size_t)(bm + arow) * K + k0 + acol);
      As[acol + 0][arow] = av.x; As[acol + 1][arow] = av.y;
      As[acol + 2][arow] = av.z; As[acol + 3][arow] = av.w;
    } else {
      const int arow = tid >> 3, acol = (tid & 7) * 2;
      float2 av = *(const float2*)(A + (size_t)(bm + arow) * K + k0 + acol);
      As[acol + 0][arow] = av.x; As[acol + 1][arow] = av.y;
    }
    *(float4*)&Bs[brow][bcol] = *(const float4*)(Bw + (size_t)(k0 + brow) * N + bn + bcol);
    __syncthreads();
#pragma unroll
    for (int k = 0; k < BK; ++k) {
      float a[TM], b[TN];
#pragma unroll
      for (int i = 0; i < TM; ++i) a[i] = As[k][ty * TM + i];
#pragma unroll
      for (int j = 0; j < TN; ++j) b[j] = Bs[k][tx * TN + j];
#pragma unroll
      for (int i = 0; i < TM; ++i)
#pragma unroll
        for (int j = 0; j < TN; ++j)
          acc[i][j] = fmaf(a[i], b[j], acc[i][j]);
    }
    __syncthreads();
  }
#pragma unroll
  for (int i = 0; i < TM; ++i) {
    int row = bm + ty * TM + i;
#pragma unroll
    for (int j = 0; j < TN; ++j) {
      int col = bn + tx * TN + j;
      float v = acc[i][j];
      if constexpr (EPI == 1) v += C[(size_t)row * ldc + col];
      if constexpr (EPI == 2) v += X[col];
      C[(size_t)row * ldc + col] = v;
    }
  }
}

// ---------------- fused GLU ff1: Act = (A@W1[:, :2048]) * gelu(A@W1[:, 2048:]) ----------------
__global__ __launch_bounds__(256) void gemm_glu_k(
    const float* __restrict__ A, const float* __restrict__ W1,
    float* __restrict__ Act, int K)
{
  constexpr int BK = 16;
  __shared__ float As[BK][68];
  __shared__ float B1s[BK][68];
  __shared__ float B2s[BK][68];
  const int tid = threadIdx.x;
  const int tx = tid & 15, ty = tid >> 4;
  const int bm = blockIdx.y * 64, bn = blockIdx.x * 64;
  const int brow = tid >> 4, bcol = (tid & 15) * 4;
  const int arow = tid >> 2, acol = (tid & 3) * 4;
  float acc1[4][4] = {}, acc2[4][4] = {};
  for (int k0 = 0; k0 < K; k0 += BK) {
    float4 av = *(const float4*)(A + (size_t)(bm + arow) * K + k0 + acol);
    As[acol + 0][arow] = av.x; As[acol + 1][arow] = av.y;
    As[acol + 2][arow] = av.z; As[acol + 3][arow] = av.w;
    *(float4*)&B1s[brow][bcol] = *(const float4*)(W1 + (size_t)(k0 + brow) * (2 * FFI_) + bn + bcol);
    *(float4*)&B2s[brow][bcol] = *(const float4*)(W1 + (size_t)(k0 + brow) * (2 * FFI_) + FFI_ + bn + bcol);
    __syncthreads();
#pragma unroll
    for (int k = 0; k < BK; ++k) {
      float a[4], b1[4], b2[4];
#pragma unroll
      for (int i = 0; i < 4; ++i) a[i] = As[k][ty * 4 + i];
#pragma unroll
      for (int j = 0; j < 4; ++j) { b1[j] = B1s[k][tx * 4 + j]; b2[j] = B2s[k][tx * 4 + j]; }
#pragma unroll
      for (int i = 0; i < 4; ++i)
#pragma unroll
        for (int j = 0; j < 4; ++j) {
          acc1[i][j] = fmaf(a[i], b1[j], acc1[i][j]);
          acc2[i][j] = fmaf(a[i], b2[j], acc2[i][j]);
        }
    }
    __syncthreads();
  }
#pragma unroll
  for (int i = 0; i < 4; ++i) {
    int row = bm + ty * 4 + i;
#pragma unroll
    for (int j = 0; j < 4; ++j) {
      int col = bn + tx * 4 + j;
      Act[(size_t)row * FFI_ + col] = acc1[i][j] * gelu_tanh(acc2[i][j]);
    }
  }
}

// ---------------- rope + scatter qkv into q buffer and KV caches ----------------
__global__ __launch_bounds__(128) void qkv_post_k(
    const float* __restrict__ qkv, float* __restrict__ qb,
    float* __restrict__ kc, float* __restrict__ vc, int t)
{
  int b = blockIdx.x, d = threadIdx.x;     // d in [0,128)
  const float* row = qkv + (size_t)b * 384;
  float qv = row[d], kv = row[128 + d], vv = row[256 + d];
  int hd = d & 63;
  if (hd < ROT_) {
    int j = (hd < 16) ? hd : hd - 16;
    float invf = 1.0f / powf(10000.0f, (float)(2 * j) * (1.0f / ROT_));
    float ang = (float)t * invf;
    float cs = cosf(ang), sn = sinf(ang);
    if (hd < 16) {
      qv = row[d] * cs - row[d + 16] * sn;
      kv = row[128 + d] * cs - row[128 + d + 16] * sn;
    } else {
      qv = row[d] * cs + row[d - 16] * sn;
      kv = row[128 + d] * cs + row[128 + d - 16] * sn;
    }
  }
  qb[(size_t)b * INNER_ + d] = qv;
  kc[((size_t)b * SEQ_ + t) * INNER_ + d] = kv;
  vc[((size_t)b * SEQ_ + t) * INNER_ + d] = vv;
}

// ---------------- attention for the single new position ----------------
__global__ __launch_bounds__(128) void attn_k(
    const float* __restrict__ qb, const float* __restrict__ kc,
    const float* __restrict__ vc, float* __restrict__ ob, int t)
{
  int b = blockIdx.x;
  int h = threadIdx.x >> 6, d = threadIdx.x & 63;
  float qd = qb[(size_t)b * INNER_ + h * DH_ + d];
  const float* kp = kc + (size_t)b * SEQ_ * INNER_ + h * DH_ + d;
  const float* vp = vc + (size_t)b * SEQ_ * INNER_ + h * DH_ + d;
  float s[SEQ_];
#pragma unroll
  for (int j = 0; j < SEQ_; ++j) {
    if (j <= t) {
      float p = qd * kp[j * INNER_];
#pragma unroll
      for (int m = 32; m; m >>= 1) p += __shfl_xor(p, m);
      s[j] = p * 0.125f;
    } else s[j] = -1e30f;
  }
  float mx = s[0];
#pragma unroll
  for (int j = 1; j < SEQ_; ++j) if (j <= t) mx = fmaxf(mx, s[j]);
  float sum = 0.0f;
#pragma unroll
  for (int j = 0; j < SEQ_; ++j) if (j <= t) { s[j] = expf(s[j] - mx); sum += s[j]; }
  float od = 0.0f;
#pragma unroll
  for (int j = 0; j < SEQ_; ++j) if (j <= t) od += (s[j] / sum) * vp[j * INNER_];
  ob[(size_t)b * INNER_ + h * DH_ + d] = od;
}

// ---------------- gumbel sample + softmax-mean + used/idx bookkeeping ----------------
// JAX >=0.4.30 default: jax_threefry_partitionable=True. random_bits for 32-bit
// element j: cipher counter (x0,x1) = (j>>32, j) = (0, j); bits = x0out ^ x1out.
__global__ __launch_bounds__(256) void sample_k(
    const float* __restrict__ logits, unsigned char* __restrict__ used,
    float* __restrict__ mp, int* __restrict__ idx_all, float* __restrict__ codes_f,
    unsigned k0, unsigned k1, int step)
{
  int b = blockIdx.x, tid = threadIdx.x;
  float mk[4], val[4];
  int cs[4];
#pragma unroll
  for (int r = 0; r < 4; ++r) {
    int c = tid + r * 256;
    unsigned j = (unsigned)(b * CLS_ + c);
    unsigned x0 = 0u, x1 = j;
    tf2x32(k0, k1, x0, x1);
    unsigned bits = x0 ^ x1;
    float f = __uint_as_float((bits >> 9) | 0x3f800000u) - 1.0f;
    float u = fmaxf(f, 1.17549435e-38f);
    float gmb = (float)(-log(-log((double)u)));
    float lg = logits[(size_t)b * CLS_ + c];
    float m = used[(size_t)b * CLS_ + c] ? -INFINITY : lg;
    mk[r] = m; val[r] = m + gmb; cs[r] = c;
  }
  float bv = val[0]; int bi = cs[0]; float bm = mk[0];
#pragma unroll
  for (int r = 1; r < 4; ++r) {
    if (val[r] > bv || (val[r] == bv && cs[r] < bi)) { bv = val[r]; bi = cs[r]; }
    bm = fmaxf(bm, mk[r]);
  }
#pragma unroll
  for (int m_ = 32; m_; m_ >>= 1) {
    float ov = __shfl_xor(bv, m_); int oi = __shfl_xor(bi, m_);
    if (ov > bv || (ov == bv && oi < bi)) { bv = ov; bi = oi; }
    bm = fmaxf(bm, __shfl_xor(bm, m_));
  }
  __shared__ float sv[4]; __shared__ int si[4]; __shared__ float sm_[4]; __shared__ float ssum[4];
  __shared__ int s_bidx; __shared__ float s_rowm; __shared__ float s_tot;
  int w = tid >> 6;
  if ((tid & 63) == 0) { sv[w] = bv; si[w] = bi; sm_[w] = bm; }
  __syncthreads();
  if (tid == 0) {
    float v = sv[0]; int ii = si[0]; float mm = sm_[0];
    for (int q = 1; q < 4; ++q) {
      if (sv[q] > v || (sv[q] == v && si[q] < ii)) { v = sv[q]; ii = si[q]; }
      mm = fmaxf(mm, sm_[q]);
    }
    s_bidx = ii; s_rowm = mm;
  }
  __syncthreads();
  float m2 = s_rowm;
  float pv[4]; float psum = 0.0f;
#pragma unroll
  for (int r = 0; r < 4; ++r) { pv[r] = expf(mk[r] - m2); psum += pv[r]; }
#pragma unroll
  for (int m_ = 32; m_; m_ >>= 1) psum += __shfl_xor(psum, m_);
  if ((tid & 63) == 0) ssum[w] = psum;
  __syncthreads();
  if (tid == 0) s_tot = ssum[0] + ssum[1] + ssum[2] + ssum[3];
  __syncthreads();
  float tot = s_tot;
#pragma unroll
  for (int r = 0; r < 4; ++r) atomicAdd(&mp[cs[r]], pv[r] / tot);
  if (tid == 0) {
    idx_all[step * B_ + b] = s_bidx;
    codes_f[step * B_ + b] = (float)s_bidx;
    used[(size_t)b * CLS_ + s_bidx] = 1;
  }
}

// ---------------- perplexity accumulate ----------------
__global__ __launch_bounds__(256) void perp_k(const float* __restrict__ mp, float* __restrict__ acc)
{
  int tid = threadIdx.x;
  float s = 0.0f;
#pragma unroll
  for (int r = 0; r < 4; ++r) {
    float m = mp[tid + r * 256] * (1.0f / (float)B_);
    s += m * logf(m + 1e-7f);
  }
#pragma unroll
  for (int m_ = 32; m_; m_ >>= 1) s += __shfl_xor(s, m_);
  __shared__ float red[4];
  if ((tid & 63) == 0) red[tid >> 6] = s;
  __syncthreads();
  if (tid == 0) *acc += expf(-(red[0] + red[1] + red[2] + red[3]));
}

// ---------------- feedback token gather: h = FT[idx] ----------------
__global__ __launch_bounds__(256) void feedback_k(const float* __restrict__ FT,
    const int* __restrict__ idx_all, float* __restrict__ h, int step)
{
  int b = blockIdx.x, tid = threadIdx.x;
  int id = idx_all[step * B_ + b];
  float4 v = ((const float4*)(FT + (size_t)id * DIM_))[tid];
  ((float4*)(h + (size_t)b * DIM_))[tid] = v;
}

// ---------------- final: results = cumsum of codebook rows ----------------
__global__ __launch_bounds__(256) void results_k(
    const float* __restrict__ CBT, const int* __restrict__ idx_all,
    float* __restrict__ outp)
{
  int b = blockIdx.x, tid = threadIdx.x;
  float4 acc = {0.f, 0.f, 0.f, 0.f};
  for (int s = 0; s < SEQ_; ++s) {
    int id = idx_all[s * B_ + b];
    float4 v = ((const float4*)(CBT + (size_t)id * ODIM_))[tid];
    acc.x += v.x; acc.y += v.y; acc.z += v.z; acc.w += v.w;
    ((float4*)(outp + ((size_t)s * B_ + b) * ODIM_))[tid] = acc;
  }
}

__global__ void write_tail_k(const float* __restrict__ perp, float* __restrict__ outp)
{
  outp[(size_t)SEQ_ * B_ * ODIM_] = perp[0] * (1.0f / (float)SEQ_);
}

// ---------------- 1024x1024 transpose (opt. zero output-row 0) ----------------
__global__ __launch_bounds__(256) void transpose_k(const float* __restrict__ in,
    float* __restrict__ out, int zero_row0)
{
  __shared__ float tile[32][33];
  int bx = blockIdx.x * 32, by = blockIdx.y * 32;
  int tx = threadIdx.x & 31, ty = threadIdx.x >> 5;
  for (int r = 0; r < 32; r += 8)
    tile[ty + r][tx] = in[(size_t)(by + ty + r) * 1024 + bx + tx];
  __syncthreads();
  for (int r = 0; r < 32; r += 8) {
    int orow = bx + ty + r;
    float v = tile[tx][ty + r];
    if (zero_row0 && orow == 0) v = 0.0f;
    out[(size_t)orow * 1024 + by + tx] = v;
  }
}

// ---------------- pack wq|wk|wv into one KxN=1024x384 weight per layer ----------------
__global__ __launch_bounds__(256) void pack_qkv_k(const float* __restrict__ wq,
    const float* __restrict__ wk, const float* __restrict__ wv, float* __restrict__ W3)
{
  int i = blockIdx.x * 256 + threadIdx.x;     // over 4*1024*384
  int c = i % 384;
  int rk = (i / 384) % 1024;
  int l = i / (384 * 1024);
  float v;
  if (c < 128)      v = wq[((size_t)l * 1024 + rk) * 128 + c];
  else if (c < 256) v = wk[((size_t)l * 1024 + rk) * 128 + (c - 128)];
  else              v = wv[((size_t)l * 1024 + rk) * 128 + (c - 256)];
  W3[i] = v;
}

extern "C" void kernel_launch(void* const* d_in, const int* in_sizes, int n_in,
                              void* d_out, int out_size, void* d_ws, size_t ws_size,
                              hipStream_t stream)
{
  const float* x       = (const float*)d_in[0];
  const float* rms1_g  = (const float*)d_in[1];
  const float* wq      = (const float*)d_in[2];
  const float* wk      = (const float*)d_in[3];
  const float* wv      = (const float*)d_in[4];
  const float* wo      = (const float*)d_in[5];
  const float* rms2_g  = (const float*)d_in[6];
  const float* ff_w1   = (const float*)d_in[7];
  const float* ff_w2   = (const float*)d_in[8];
  const float* final_g = (const float*)d_in[9];
  const float* cls_w   = (const float*)d_in[10];
  const float* cls_b   = (const float*)d_in[11];
  const float* fb_w    = (const float*)d_in[12];
  const float* cb_w    = (const float*)d_in[13];
  float* outp = (float*)d_out;

  // workspace layout (~130 MB)
  char* base = (char*)d_ws;
  size_t off = 0;
  auto alloc = [&](size_t bytes) -> void* {
    void* p = base + off;
    off = (off + bytes + 255) & ~(size_t)255;
    return p;
  };
  float* h      = (float*)alloc((size_t)B_ * DIM_ * 4);
  float* n      = (float*)alloc((size_t)B_ * DIM_ * 4);
  float* qkv    = (float*)alloc((size_t)B_ * 384 * 4);
  float* qb     = (float*)alloc((size_t)B_ * INNER_ * 4);
  float* ob     = (float*)alloc((size_t)B_ * INNER_ * 4);
  float* act    = (float*)alloc((size_t)B_ * FFI_ * 4);
  float* logits = (float*)alloc((size_t)B_ * CLS_ * 4);
  float* kcache = (float*)alloc((size_t)DEPTH_ * B_ * SEQ_ * INNER_ * 4);
  float* vcache = (float*)alloc((size_t)DEPTH_ * B_ * SEQ_ * INNER_ * 4);
  float* W3     = (float*)alloc((size_t)DEPTH_ * DIM_ * 384 * 4);
  float* WclsT  = (float*)alloc((size_t)DIM_ * CLS_ * 4);
  float* FT     = (float*)alloc((size_t)CLS_ * DIM_ * 4);
  float* CBT    = (float*)alloc((size_t)CLS_ * ODIM_ * 4);
  float* mp     = (float*)alloc((size_t)CLS_ * 4);
  float* perp   = (float*)alloc(256);
  int*   idx_all= (int*)alloc((size_t)SEQ_ * B_ * 4);
  unsigned char* used = (unsigned char*)alloc((size_t)B_ * CLS_);

  // per-step gumbel keys: fold_in(key(42), i) = threefry_2x32([0,42], [0,i])
  unsigned key0[SEQ_], key1[SEQ_];
  for (int i = 0; i < SEQ_; ++i) {
    unsigned a = 0u, b = (unsigned)i;
    tf2x32(0u, 42u, a, b);
    key0[i] = a; key1[i] = b;
  }

  hipMemsetAsync(used, 0, (size_t)B_ * CLS_, stream);
  hipMemsetAsync(perp, 0, 4, stream);
  pack_qkv_k<<<(DEPTH_ * DIM_ * 384) / 256, 256, 0, stream>>>(wq, wk, wv, W3);
  {
    dim3 tg(32, 32);
    transpose_k<<<tg, 256, 0, stream>>>(cls_w, WclsT, 0);
    transpose_k<<<tg, 256, 0, stream>>>(fb_w, FT, 0);
    transpose_k<<<tg, 256, 0, stream>>>(cb_w, CBT, 1);
  }
  hipMemcpyAsync(h, x, (size_t)B_ * DIM_ * 4, hipMemcpyDeviceToDevice, stream);

  float* codes_f = outp + (size_t)SEQ_ * B_ * ODIM_ + 1;

  for (int t = 0; t < SEQ_; ++t) {
    for (int l = 0; l < DEPTH_; ++l) {
      float* kc = kcache + (size_t)l * B_ * SEQ_ * INNER_;
      float* vc = vcache + (size_t)l * B_ * SEQ_ * INNER_;
      rmsnorm_k<<<B_, 256, 0, stream>>>(h, rms1_g + (size_t)l * DIM_, n);
      {
        dim3 g(384 / 64, B_ / 32);
        gemm_k<32, 2, 0><<<g, 256, 0, stream>>>(n, W3 + (size_t)l * DIM_ * 384, qkv, nullptr, 384, DIM_, 384);
      }
      qkv_post_k<<<B_, 128, 0, stream>>>(qkv, qb, kc, vc, t);
      attn_k<<<B_, 128, 0, stream>>>(qb, kc, vc, ob, t);
      {
        dim3 g(DIM_ / 64, B_ / 64);
        gemm_k<64, 4, 1><<<g, 256, 0, stream>>>(ob, wo + (size_t)l * INNER_ * DIM_, h, nullptr, DIM_, INNER_, DIM_);
      }
      rmsnorm_k<<<B_, 256, 0, stream>>>(h, rms2_g + (size_t)l * DIM_, n);
      {
        dim3 g(FFI_ / 64, B_ / 64);
        gemm_glu_k<<<g, 256, 0, stream>>>(n, ff_w1 + (size_t)l * DIM_ * 2 * FFI_, act, DIM_);
      }
      {
        dim3 g(DIM_ / 64, B_ / 64);
        gemm_k<64, 4, 1><<<g, 256, 0, stream>>>(act, ff_w2 + (size_t)l * FFI_ * DIM_, h, nullptr, DIM_, FFI_, DIM_);
      }
    }
    rmsnorm_k<<<B_, 256, 0, stream>>>(h, final_g, n);
    {
      dim3 g(CLS_ / 64, B_ / 64);
      gemm_k<64, 4, 2><<<g, 256, 0, stream>>>(n, WclsT, logits, cls_b, CLS_, DIM_, CLS_);
    }
    hipMemsetAsync(mp, 0, (size_t)CLS_ * 4, stream);
    sample_k<<<B_, 256, 0, stream>>>(logits, used, mp, idx_all, codes_f, key0[t], key1[t], t);
    perp_k<<<1, 256, 0, stream>>>(mp, perp);
    if (t + 1 < SEQ_)
      feedback_k<<<B_, 256, 0, stream>>>(FT, idx_all, h, t);
  }

  results_k<<<B_, 256, 0, stream>>>(CBT, idx_all, outp);
  write_tail_k<<<1, 1, 0, stream>>>(perp, outp);
}